// Round 1
// baseline (2043.242 us; speedup 1.0000x reference)
//
#include <hip/hip_runtime.h>

#define N_ROWS 32768
#define KCODES 8192
#define CDIM   256

#define BM 128
#define BN 128
#define CCHUNK 64
#define LSTRIDE 68   // 64 + 4 pad: keeps float4 alignment (68*4 % 16 == 0), spreads banks

// One wave per row: sum of squares (fp32), matches np within ~1 ulp (bin-shift invariant)
__global__ void rowsq_kernel(const float* __restrict__ src, float* __restrict__ dst, int nrows) {
    int wave = (blockIdx.x * blockDim.x + threadIdx.x) >> 6;
    int lane = threadIdx.x & 63;
    if (wave >= nrows) return;
    float4 v = *((const float4*)src + (size_t)wave * (CDIM / 4) + lane);
    float s = v.x * v.x + v.y * v.y + v.z * v.z + v.w * v.w;
    for (int off = 32; off; off >>= 1) s += __shfl_down(s, off, 64);
    if (lane == 0) dst[wave] = s;
}

__launch_bounds__(256, 1)
__global__ void vq_main_kernel(const float* __restrict__ x, const float* __restrict__ w,
                               const float* __restrict__ term1, const float* __restrict__ e2,
                               float* __restrict__ out_q, float* __restrict__ out_i) {
    __shared__ float xs[BM * LSTRIDE];
    __shared__ float es[BN * LSTRIDE];
    __shared__ float red_v[BM][17];
    __shared__ int   red_i[BM][17];
    __shared__ int   idx_final[BM];

    const int t  = threadIdx.x;
    const int tx = t & 15;   // code group
    const int ty = t >> 4;   // row group
    const int n0 = blockIdx.x * BM;

    float minv[8];
    int   mini[8];
    float t1[8];
#pragma unroll
    for (int rr = 0; rr < 8; ++rr) {
        minv[rr] = 3.402823466e38f;
        mini[rr] = 0;
        t1[rr]   = term1[n0 + ty + rr * 16];
    }

    for (int kt = 0; kt < KCODES / BN; ++kt) {
        const int k0 = kt * BN;
        float acc[8][8];
#pragma unroll
        for (int rr = 0; rr < 8; ++rr)
#pragma unroll
            for (int kk = 0; kk < 8; ++kk) acc[rr][kk] = 0.f;

        for (int cc = 0; cc < CDIM / CCHUNK; ++cc) {
            __syncthreads();
            // stage x tile: 128 rows x 64 cols (coalesced 256B segments)
#pragma unroll
            for (int j = 0; j < 8; ++j) {
                int flat = j * 256 + t;
                int row  = flat >> 4;
                int c4   = flat & 15;
                float4 v = *((const float4*)x + (size_t)(n0 + row) * (CDIM / 4) + cc * (CCHUNK / 4) + c4);
                *(float4*)&xs[row * LSTRIDE + c4 * 4] = v;
            }
            // stage e tile: 128 codes x 64 cols
#pragma unroll
            for (int j = 0; j < 8; ++j) {
                int flat = j * 256 + t;
                int row  = flat >> 4;
                int c4   = flat & 15;
                float4 v = *((const float4*)w + (size_t)(k0 + row) * (CDIM / 4) + cc * (CCHUNK / 4) + c4);
                *(float4*)&es[row * LSTRIDE + c4 * 4] = v;
            }
            __syncthreads();
#pragma unroll 1
            for (int c4 = 0; c4 < 16; ++c4) {
                float4 xf[8], ef[8];
#pragma unroll
                for (int rr = 0; rr < 8; ++rr)
                    xf[rr] = *(const float4*)&xs[(ty + rr * 16) * LSTRIDE + c4 * 4];
#pragma unroll
                for (int kk = 0; kk < 8; ++kk)
                    ef[kk] = *(const float4*)&es[(tx + kk * 16) * LSTRIDE + c4 * 4];
#pragma unroll
                for (int rr = 0; rr < 8; ++rr)
#pragma unroll
                    for (int kk = 0; kk < 8; ++kk) {
                        acc[rr][kk] = fmaf(xf[rr].x, ef[kk].x, acc[rr][kk]);
                        acc[rr][kk] = fmaf(xf[rr].y, ef[kk].y, acc[rr][kk]);
                        acc[rr][kk] = fmaf(xf[rr].z, ef[kk].z, acc[rr][kk]);
                        acc[rr][kk] = fmaf(xf[rr].w, ef[kk].w, acc[rr][kk]);
                    }
            }
        }
        // epilogue: d = fl(fl(term1+e2) - 2*s), strict < keeps earliest k (np argmin tie rule)
#pragma unroll
        for (int kk = 0; kk < 8; ++kk) {
            int   kg  = k0 + tx + kk * 16;
            float e2k = e2[kg];
#pragma unroll
            for (int rr = 0; rr < 8; ++rr) {
                float A = t1[rr] + e2k;
                float d = A - 2.0f * acc[rr][kk];   // 2*s exact; single rounding like np
                if (d < minv[rr]) { minv[rr] = d; mini[rr] = kg; }
            }
        }
    }

    // cross-thread (16 candidates per row) reduction with first-index tie-break
    __syncthreads();
#pragma unroll
    for (int rr = 0; rr < 8; ++rr) {
        red_v[ty + rr * 16][tx] = minv[rr];
        red_i[ty + rr * 16][tx] = mini[rr];
    }
    __syncthreads();
    if (t < BM) {
        float v  = red_v[t][0];
        int   bi = red_i[t][0];
        for (int j = 1; j < 16; ++j) {
            float vj = red_v[t][j];
            int   ij = red_i[t][j];
            if (vj < v || (vj == v && ij < bi)) { v = vj; bi = ij; }
        }
        idx_final[t] = bi;
        out_i[n0 + t] = (float)bi;   // indices as fp32 (exact up to 2^24)
    }
    __syncthreads();

    // fused gather: out_q[row] = weight[idx[row]]
    for (int j = 0; j < 32; ++j) {
        int flat = j * 256 + t;     // over 128 rows x 64 float4
        int lr   = flat >> 6;
        int c4   = flat & 63;
        int code = idx_final[lr];
        float4 v = *((const float4*)w + (size_t)code * (CDIM / 4) + c4);
        *((float4*)out_q + (size_t)(n0 + lr) * (CDIM / 4) + c4) = v;
    }
}

extern "C" void kernel_launch(void* const* d_in, const int* in_sizes, int n_in,
                              void* d_out, int out_size, void* d_ws, size_t ws_size,
                              hipStream_t stream) {
    const float* x = (const float*)d_in[0];   // (8,4096,256) fp32
    const float* w = (const float*)d_in[1];   // (8192,256) fp32

    float* out_q = (float*)d_out;                       // N*C quantized
    float* out_i = out_q + (size_t)N_ROWS * CDIM;       // N indices (as float)

    float* e2 = (float*)d_ws;           // K floats
    float* t1 = e2 + KCODES;            // N floats

    rowsq_kernel<<<KCODES / 4, 256, 0, stream>>>(w, e2, KCODES);
    rowsq_kernel<<<N_ROWS / 4, 256, 0, stream>>>(x, t1, N_ROWS);
    vq_main_kernel<<<N_ROWS / BM, 256, 0, stream>>>(x, w, t1, e2, out_q, out_i);
}

// Round 2
// 740.505 us; speedup vs baseline: 2.7593x; 2.7593x over previous
//
#include <hip/hip_runtime.h>
#include <hip/hip_fp16.h>

#define N_ROWS 32768
#define KCODES 8192
#define CDIM   256
#define NSUB   (KCODES / 16)     // 512 subtiles of 16 codes
#define MARGIN 6.0e-4f
#define LSTR   72                // LDS row stride in bf16 units (64 + 8 pad)

typedef __attribute__((ext_vector_type(8))) short bf16x8;
typedef __attribute__((ext_vector_type(4))) float f32x4;

// ---------- phase 0: fp32 -> bf16 (RNE bit-trick), vectorized ----------
__global__ void cvt_bf16_kernel(const float* __restrict__ src, ushort* __restrict__ dst, int n8) {
    int i = blockIdx.x * blockDim.x + threadIdx.x;
    if (i >= n8) return;
    float4 a = ((const float4*)src)[i * 2];
    float4 b = ((const float4*)src)[i * 2 + 1];
    float v[8] = {a.x, a.y, a.z, a.w, b.x, b.y, b.z, b.w};
    union { ushort s[8]; uint4 u; } r;
#pragma unroll
    for (int j = 0; j < 8; ++j) {
        unsigned u = __float_as_uint(v[j]);
        u += 0x7fffu + ((u >> 16) & 1u);        // round-to-nearest-even
        r.s[j] = (ushort)(u >> 16);
    }
    *(uint4*)(dst + (size_t)i * 8) = r.u;
}

// ---------- phase 0: row sum-of-squares (same as round 1 -> same t1/e2 values) ----------
__global__ void rowsq_kernel(const float* __restrict__ src, float* __restrict__ dst, int nrows) {
    int wave = (blockIdx.x * blockDim.x + threadIdx.x) >> 6;
    int lane = threadIdx.x & 63;
    if (wave >= nrows) return;
    float4 v = *((const float4*)src + (size_t)wave * (CDIM / 4) + lane);
    float s = v.x * v.x + v.y * v.y + v.z * v.z + v.w * v.w;
    for (int off = 32; off; off >>= 1) s += __shfl_down(s, off, 64);
    if (lane == 0) dst[wave] = s;
}

// ---------- phase 1: bf16 MFMA scores, per-(row,16-code-subtile) minima of (e2 - 2s) ----------
__launch_bounds__(256, 2)
__global__ void vq_mfma_kernel(const ushort* __restrict__ xb, const ushort* __restrict__ wb,
                               const float* __restrict__ e2, __half* __restrict__ minT) {
    __shared__ ushort xs[128 * LSTR];
    __shared__ ushort ws[128 * LSTR];
    __shared__ __align__(16) __half mb[128][8];

    const int t = threadIdx.x;
    const int w = t >> 6, lane = t & 63;
    const int ln15 = lane & 15, quad = lane >> 4;
    const int rt = blockIdx.x >> 6;      // 256 row tiles   (64 consecutive blocks share X tile)
    const int ct = blockIdx.x & 63;      // 64 code tiles
    const int rbase = (w >> 1) * 64, cbase = (w & 1) * 64;

    f32x4 acc[4][4];
#pragma unroll
    for (int mi = 0; mi < 4; ++mi)
#pragma unroll
        for (int ni = 0; ni < 4; ++ni)
#pragma unroll
            for (int r = 0; r < 4; ++r) acc[mi][ni][r] = 0.f;

    for (int cc = 0; cc < 4; ++cc) {                  // K chunks of 64
        __syncthreads();
#pragma unroll
        for (int j = 0; j < 4; ++j) {                 // stage 128x64 bf16 of X and W
            int flat = j * 256 + t;
            int row = flat >> 3, c8 = flat & 7;
            uint4 vx = *(const uint4*)(xb + (size_t)(rt * 128 + row) * CDIM + cc * 64 + c8 * 8);
            *(uint4*)&xs[row * LSTR + c8 * 8] = vx;
            uint4 vw = *(const uint4*)(wb + (size_t)(ct * 128 + row) * CDIM + cc * 64 + c8 * 8);
            *(uint4*)&ws[row * LSTR + c8 * 8] = vw;
        }
        __syncthreads();
#pragma unroll
        for (int ks = 0; ks < 2; ++ks) {              // two k=32 MFMA steps per chunk
            bf16x8 a[4], b[4];
#pragma unroll
            for (int mi = 0; mi < 4; ++mi)
                a[mi] = *(const bf16x8*)&xs[(rbase + mi * 16 + ln15) * LSTR + ks * 32 + quad * 8];
#pragma unroll
            for (int ni = 0; ni < 4; ++ni)
                b[ni] = *(const bf16x8*)&ws[(cbase + ni * 16 + ln15) * LSTR + ks * 32 + quad * 8];
#pragma unroll
            for (int mi = 0; mi < 4; ++mi)
#pragma unroll
                for (int ni = 0; ni < 4; ++ni)
                    acc[mi][ni] = __builtin_amdgcn_mfma_f32_16x16x32_bf16(a[mi], b[ni], acc[mi][ni], 0, 0, 0);
        }
    }

    // epilogue: r~ = e2[col] - 2*s ; min over the 16 cols of each subtile
    float e2l[4];
#pragma unroll
    for (int ni = 0; ni < 4; ++ni) e2l[ni] = e2[ct * 128 + cbase + ni * 16 + ln15];
#pragma unroll
    for (int mi = 0; mi < 4; ++mi)
#pragma unroll
        for (int ni = 0; ni < 4; ++ni)
#pragma unroll
            for (int reg = 0; reg < 4; ++reg) {
                float r = e2l[ni] - 2.0f * acc[mi][ni][reg];
#pragma unroll
                for (int off = 1; off < 16; off <<= 1) r = fminf(r, __shfl_xor(r, off, 64));
                if (ln15 == 0)
                    mb[rbase + mi * 16 + quad * 4 + reg][(cbase >> 4) + ni] = __float2half(r);
            }
    __syncthreads();
    if (t < 128) {
        uint4 v = *(uint4*)&mb[t][0];                              // 8 halves = 16 B
        *(uint4*)(minT + ((size_t)(rt * 128 + t)) * NSUB + ct * 8) = v;
    }
}

// ---------- phase 2: exact fp32 re-rank of candidate subtiles + fused gather ----------
__launch_bounds__(256, 2)
__global__ void vq_rerank_kernel(const float* __restrict__ x, const float* __restrict__ wgt,
                                 const float* __restrict__ t1, const float* __restrict__ e2,
                                 const __half* __restrict__ minT,
                                 float* __restrict__ out_q, float* __restrict__ out_i) {
    __shared__ float xrow[4][256];
    __shared__ int slist[4][40];
    const int t = threadIdx.x, w = t >> 6, lane = t & 63, quad = lane >> 4;
    const int row = blockIdx.x * 4 + w;

    // stage x row (1 KB) into LDS
    *(float4*)&xrow[w][lane * 4] = *((const float4*)(x + (size_t)row * CDIM) + lane);

    // read 512 subtile minima (8 per lane), wave-reduce the global approx min
    union { uint4 u; __half2 h2[4]; } raw;
    raw.u = *((const uint4*)(minT + (size_t)row * NSUB) + lane);
    float m[8];
#pragma unroll
    for (int i = 0; i < 4; ++i) {
        float2 f = __half22float2(raw.h2[i]);
        m[2 * i] = f.x;
        m[2 * i + 1] = f.y;
    }
    float lmin = m[0];
#pragma unroll
    for (int i = 1; i < 8; ++i) lmin = fminf(lmin, m[i]);
#pragma unroll
    for (int off = 1; off < 64; off <<= 1) lmin = fminf(lmin, __shfl_xor(lmin, off, 64));
    const float thresh = lmin + MARGIN;

    // build candidate subtile list (certified superset of exact-min-bin codes)
    int base = 0;
#pragma unroll
    for (int s = 0; s < 8; ++s) {
        bool c = (m[s] <= thresh);
        unsigned long long mask = __ballot(c);
        if (c) {
            int pos = base + __popcll(mask & ((1ull << lane) - 1ull));
            if (pos < 40) slist[w][pos] = lane * 8 + s;
        }
        base += (int)__popcll(mask);
    }
    const int ncand = base < 40 ? base : 40;
    __syncthreads();

    const float t1r = t1[row];
    float best = 3.402823466e38f;
    int bestk = 0x7fffffff;
    for (int p = 0; p * 4 < ncand; ++p) {
        int li = p * 4 + quad;                 // 4 subtiles per pass, 16 lanes each
        float d = 3.402823466e38f;
        int k = 0x7fffffff;
        if (li < ncand) {
            int st = slist[w][li];
            k = st * 16 + (lane & 15);
            // EXACT round-1 accumulation order: sequential c = 0..255, fmaf chain
            float acc = 0.f;
            const float4* wp = (const float4*)(wgt + (size_t)k * CDIM);
            for (int c4 = 0; c4 < 64; ++c4) {
                float4 wv = wp[c4];
                float4 xv = *(const float4*)&xrow[w][c4 * 4];
                acc = fmaf(xv.x, wv.x, acc);
                acc = fmaf(xv.y, wv.y, acc);
                acc = fmaf(xv.z, wv.z, acc);
                acc = fmaf(xv.w, wv.w, acc);
            }
            d = (t1r + e2[k]) - 2.0f * acc;    // same quantization chain as np / round 1
        }
        if (d < best || (d == best && k < bestk)) { best = d; bestk = k; }
    }
    // wave-reduce (d, k) with first-index tie-break (np argmin semantics)
#pragma unroll
    for (int off = 1; off < 64; off <<= 1) {
        float od = __shfl_xor(best, off, 64);
        int ok = __shfl_xor(bestk, off, 64);
        if (od < best || (od == best && ok < bestk)) { best = od; bestk = ok; }
    }

    // fused gather + index write
    const float4* src = (const float4*)(wgt + (size_t)bestk * CDIM);
    ((float4*)(out_q + (size_t)row * CDIM))[lane] = src[lane];
    if (lane == 0) out_i[row] = (float)bestk;
}

extern "C" void kernel_launch(void* const* d_in, const int* in_sizes, int n_in,
                              void* d_out, int out_size, void* d_ws, size_t ws_size,
                              hipStream_t stream) {
    const float* x = (const float*)d_in[0];   // (8,4096,256) fp32
    const float* wgt = (const float*)d_in[1]; // (8192,256) fp32

    float* out_q = (float*)d_out;
    float* out_i = out_q + (size_t)N_ROWS * CDIM;

    // workspace carve (all 16B aligned): e2, t1, minT, xb, wb  -> ~52.3 MB
    char* p = (char*)d_ws;
    float* e2 = (float*)p;               p += (size_t)KCODES * 4;
    float* t1 = (float*)p;               p += (size_t)N_ROWS * 4;
    __half* minT = (__half*)p;           p += (size_t)N_ROWS * NSUB * 2;
    ushort* xb = (ushort*)p;             p += (size_t)N_ROWS * CDIM * 2;
    ushort* wb = (ushort*)p;             p += (size_t)KCODES * CDIM * 2;

    cvt_bf16_kernel<<<(N_ROWS * CDIM / 8 + 255) / 256, 256, 0, stream>>>(x, xb, N_ROWS * CDIM / 8);
    cvt_bf16_kernel<<<(KCODES * CDIM / 8 + 255) / 256, 256, 0, stream>>>(wgt, wb, KCODES * CDIM / 8);
    rowsq_kernel<<<KCODES / 4, 256, 0, stream>>>(wgt, e2, KCODES);
    rowsq_kernel<<<N_ROWS / 4, 256, 0, stream>>>(x, t1, N_ROWS);

    vq_mfma_kernel<<<(N_ROWS / 128) * (KCODES / 128), 256, 0, stream>>>(xb, wb, e2, minT);
    vq_rerank_kernel<<<N_ROWS / 4, 256, 0, stream>>>(x, wgt, t1, e2, minT, out_q, out_i);
}